// Round 6
// baseline (211.749 us; speedup 1.0000x reference)
//
#include <hip/hip_runtime.h>
#include <hip/hip_bf16.h>
#include <cstdint>
#include <cstddef>

#define VOCAB 32000
#define HIDDEN 2048
#define NLAYERS 6
#define BATCH 512

// Full-K fused GEMM: M=512, N=2048, K=2048 per layer.
// BM=64 x BN=32 -> grid (64,8) = 512 blocks = 2/CU x 4 waves (barrier stagger).
// gridDim.x=64 === 0 mod 8: all blocks sharing a B-panel land on one XCD ->
// B re-reads are XCD-local L2 hits (8 panels x 128 KB + A 2 MB < 4 MB L2).
#define BM 64
#define BN 32
#define BK 64
#define NT (HIDDEN / BK)  // 32 K-tiles

typedef __attribute__((ext_vector_type(8))) short bf16x8;
typedef __attribute__((ext_vector_type(4))) float f32x4;

__device__ __forceinline__ unsigned short f2bf(float f) {
  unsigned u = __builtin_bit_cast(unsigned, f);
  u += 0x7fffu + ((u >> 16) & 1u);  // RNE
  return (unsigned short)(u >> 16);
}

__device__ __forceinline__ float tanh_fast(float x) {
  x = fminf(15.f, fmaxf(-15.f, x));
  float e = __expf(2.f * x);
  return (e - 1.f) / (e + 1.f);
}

__device__ __forceinline__ void gload_lds16(const void* g, void* l) {
  __builtin_amdgcn_global_load_lds(
      (const __attribute__((address_space(1))) void*)g,
      (__attribute__((address_space(3))) void*)l, 16, 0, 0);
}

// ---- prep: z<NLAYERS: hh[l] fp32 [K][N] -> Bt bf16 [N][K]; z==NLAYERS: cvt state ----
__global__ __launch_bounds__(256) void k_prep(const float* __restrict__ hh,
                                              unsigned short* __restrict__ bt,
                                              const float* __restrict__ state,
                                              unsigned short* __restrict__ stb) {
  const int l = blockIdx.z;
  const int t = threadIdx.x;
  if (l == NLAYERS) {
    const int bid = blockIdx.y * 32 + blockIdx.x;
    const int i = (bid * 256 + t) * 4;
    float4 v = *(const float4*)(state + i);
    union { unsigned short h[4]; uint2 u; } o;
    o.h[0] = f2bf(v.x); o.h[1] = f2bf(v.y); o.h[2] = f2bf(v.z); o.h[3] = f2bf(v.w);
    *(uint2*)(stb + i) = o.u;
    return;
  }
  __shared__ unsigned short tile[64][72];  // padded to dodge bank conflicts
  const int n0 = blockIdx.x * 64;
  const int k0 = blockIdx.y * 64;
  const float* src = hh + ((size_t)l * HIDDEN + k0) * HIDDEN + n0;
  const int cr = t >> 4;        // 0..15
  const int cc = (t & 15) * 4;  // 0..60
#pragma unroll
  for (int p = 0; p < 4; ++p) {
    const int r = p * 16 + cr;
    float4 v = *(const float4*)(src + (size_t)r * HIDDEN + cc);
    tile[r][cc + 0] = f2bf(v.x);
    tile[r][cc + 1] = f2bf(v.y);
    tile[r][cc + 2] = f2bf(v.z);
    tile[r][cc + 3] = f2bf(v.w);
  }
  __syncthreads();
  const int nl = t >> 2;        // output row (n), 0..63
  const int kk = (t & 3) * 16;  // k chunk
  unsigned short tmp[16] __attribute__((aligned(16)));
#pragma unroll
  for (int j = 0; j < 16; ++j) tmp[j] = tile[kk + j][nl];
  unsigned short* dst = bt + ((size_t)l * HIDDEN + n0 + nl) * HIDDEN + k0 + kk;
  *(uint4*)(dst) = *(const uint4*)(tmp);
  *(uint4*)(dst + 8) = *(const uint4*)(tmp + 8);
}

// ---- fused layer: full-K GEMM + epilogue (gate, residual, tanh, dual store) ----
// grid (64, 8), 256 threads = 4 waves (2M x 2N), wave tile 32x16.
__global__ __launch_bounds__(256, 2) void k_gemm_fused(
    const unsigned short* __restrict__ A, const unsigned short* __restrict__ Bt,
    const float* __restrict__ prev, const float* __restrict__ ihl,
    const int* __restrict__ token, float* __restrict__ outf,
    unsigned short* __restrict__ outb) {
  __shared__ __attribute__((aligned(16))) unsigned short As[2][BM][BK];  // 16 KB
  __shared__ __attribute__((aligned(16))) unsigned short Bs[2][BN][BK];  //  8 KB

  const int n0 = blockIdx.x * BN;
  const int m0 = blockIdx.y * BM;
  const int t = threadIdx.x;
  const int lane = t & 63;
  const int wid = t >> 6;
  const int wm = (wid >> 1) * 32;  // 0 / 32
  const int wn = (wid & 1) * 16;   // 0 / 16

  f32x4 zero = {0.f, 0.f, 0.f, 0.f};
  f32x4 acc[2];
  acc[0] = zero; acc[1] = zero;

  // T2 both-sides swizzle: pre-swizzled global source + linear LDS dest +
  // swizzled ds_read. A tile = 512 chunks (thread t: chunks t, t+256 -> rows
  // r0, r0+32; (r+32)&7 == r&7). B tile = 256 chunks (thread t: chunk t).
  const int r0 = t >> 3;                    // 0..31
  const int sc = ((t & 7) ^ (r0 & 7)) * 8;  // swizzled k-chunk (elements)
  const unsigned short* gA = A + (size_t)(m0 + r0) * HIDDEN + sc;
  const unsigned short* gB = Bt + (size_t)(n0 + r0) * HIDDEN + sc;
  char* lA = (char*)&As[0][0][0] + wid * 1024;  // + lane*16 implicit
  char* lB = (char*)&Bs[0][0][0] + wid * 1024;

#define STAGE(buf, kt)                                          \
  do {                                                          \
    const int ko = (kt)*BK;                                     \
    gload_lds16(gA + ko, lA + (buf)*8192);                      \
    gload_lds16(gA + 32 * HIDDEN + ko, lA + (buf)*8192 + 4096); \
    gload_lds16(gB + ko, lB + (buf)*4096);                      \
  } while (0)

  const int ra = wm + (lane & 15);  // A rows ra, ra+16
  const int rb = wn + (lane & 15);  // B row
  const int q = lane >> 4;          // 0..3

#define COMPUTE(buf)                                                              \
  do {                                                                            \
    _Pragma("unroll") for (int ks = 0; ks < 2; ++ks) {                            \
      const int cnk = ks * 4 + q;                                                 \
      bf16x8 a0 = *(const bf16x8*)&As[buf][ra][(cnk ^ (ra & 7)) * 8];             \
      bf16x8 a1 = *(const bf16x8*)&As[buf][ra + 16][(cnk ^ ((ra + 16) & 7)) * 8]; \
      bf16x8 b0 = *(const bf16x8*)&Bs[buf][rb][(cnk ^ (rb & 7)) * 8];             \
      acc[0] = __builtin_amdgcn_mfma_f32_16x16x32_bf16(a0, b0, acc[0], 0, 0, 0);  \
      acc[1] = __builtin_amdgcn_mfma_f32_16x16x32_bf16(a1, b0, acc[1], 0, 0, 0);  \
    }                                                                             \
  } while (0)

  STAGE(0, 0);
  __syncthreads();
  for (int kt = 0; kt < NT; ++kt) {
    const int buf = kt & 1;
    if (kt + 1 < NT) STAGE(buf ^ 1, kt + 1);
    COMPUTE(buf);
    __syncthreads();
  }

  // Fused epilogue: state' = tanh(prev + C * ih[token]); write f32 (+bf16).
  const int orow = m0 + wm + (q << 2);
  const int ocol = n0 + wn + (lane & 15);
#pragma unroll
  for (int fm = 0; fm < 2; ++fm) {
#pragma unroll
    for (int j = 0; j < 4; ++j) {
      const int r = orow + fm * 16 + j;
      const int tok = token[r];
      const float g = ihl[(size_t)tok * HIDDEN + ocol];
      const float pv = prev[(size_t)r * HIDDEN + ocol];
      const float v = tanh_fast(pv + acc[fm][j] * g);
      outf[(size_t)r * HIDDEN + ocol] = v;
      if (outb) outb[(size_t)r * HIDDEN + ocol] = f2bf(v);
    }
  }
}

extern "C" void kernel_launch(void* const* d_in, const int* in_sizes, int n_in,
                              void* d_out, int out_size, void* d_ws, size_t ws_size,
                              hipStream_t stream) {
  const float* state = (const float*)d_in[0];
  const int* token = (const int*)d_in[1];
  const float* ih = (const float*)d_in[2];
  const float* hh = (const float*)d_in[3];
  float* out = (float*)d_out;

  // ws layout (16B-aligned):
  //   Bt  : 6*2048*2048 bf16 = 50331648 B
  //   stb : 512*2048 bf16    =  2097152 B
  //   sf  : 512*2048 f32     =  4194304 B
  char* ws = (char*)d_ws;
  unsigned short* bt = (unsigned short*)ws;
  size_t off = (size_t)NLAYERS * HIDDEN * HIDDEN * 2;
  unsigned short* stb = (unsigned short*)(ws + off);
  off += (size_t)BATCH * HIDDEN * 2;
  float* sf = (float*)(ws + off);

  k_prep<<<dim3(HIDDEN / 64, HIDDEN / 64, NLAYERS + 1), 256, 0, stream>>>(hh, bt, state, stb);

  for (int l = 0; l < NLAYERS; ++l) {
    const bool last = (l == NLAYERS - 1);
    k_gemm_fused<<<dim3(HIDDEN / BN, BATCH / BM), 256, 0, stream>>>(
        stb, bt + (size_t)l * HIDDEN * HIDDEN,
        l == 0 ? state : sf, ih + (size_t)l * VOCAB * HIDDEN, token,
        last ? out : sf, last ? nullptr : stb);
  }
}

// Round 7
// 133.184 us; speedup vs baseline: 1.5899x; 1.5899x over previous
//
#include <hip/hip_runtime.h>
#include <hip/hip_bf16.h>
#include <cstdint>
#include <cstddef>

#define VOCAB 32000
#define HIDDEN 2048
#define NLAYERS 6
#define BATCH 512

// GEMM tiling (round-4 proven structure): M=512, N=2048, K=2048 per layer
#define BM 64
#define BN 64
#define BK 64
#define SPLITK 4
#define KC (HIDDEN / SPLITK)  // 512 K per block
#define NT (KC / BK)          // 8 K-tiles

typedef __attribute__((ext_vector_type(8))) short bf16x8;
typedef __attribute__((ext_vector_type(4))) float f32x4;

__device__ __forceinline__ unsigned short f2bf(float f) {
  unsigned u = __builtin_bit_cast(unsigned, f);
  u += 0x7fffu + ((u >> 16) & 1u);  // RNE
  return (unsigned short)(u >> 16);
}

__device__ __forceinline__ float bf2f(unsigned short h) {
  return __builtin_bit_cast(float, (unsigned)h << 16);
}

__device__ __forceinline__ float tanh_fast(float x) {
  x = fminf(15.f, fmaxf(-15.f, x));
  float e = __expf(2.f * x);
  return (e - 1.f) / (e + 1.f);
}

__device__ __forceinline__ void gload_lds16(const void* g, void* l) {
  __builtin_amdgcn_global_load_lds(
      (const __attribute__((address_space(1))) void*)g,
      (__attribute__((address_space(3))) void*)l, 16, 0, 0);
}

// ---- prep: z<NLAYERS: hh[l] fp32 [K][N] -> Bt bf16 [N][K]; z==NLAYERS: cvt state ----
__global__ __launch_bounds__(256) void k_prep(const float* __restrict__ hh,
                                              unsigned short* __restrict__ bt,
                                              const float* __restrict__ state,
                                              unsigned short* __restrict__ stb) {
  const int l = blockIdx.z;
  const int t = threadIdx.x;
  if (l == NLAYERS) {
    const int bid = blockIdx.y * 32 + blockIdx.x;
    const int i = (bid * 256 + t) * 4;
    float4 v = *(const float4*)(state + i);
    union { unsigned short h[4]; uint2 u; } o;
    o.h[0] = f2bf(v.x); o.h[1] = f2bf(v.y); o.h[2] = f2bf(v.z); o.h[3] = f2bf(v.w);
    *(uint2*)(stb + i) = o.u;
    return;
  }
  __shared__ unsigned short tile[64][72];  // padded to dodge bank conflicts
  const int n0 = blockIdx.x * 64;
  const int k0 = blockIdx.y * 64;
  const float* src = hh + ((size_t)l * HIDDEN + k0) * HIDDEN + n0;
  const int cr = t >> 4;        // 0..15
  const int cc = (t & 15) * 4;  // 0..60
#pragma unroll
  for (int p = 0; p < 4; ++p) {
    const int r = p * 16 + cr;
    float4 v = *(const float4*)(src + (size_t)r * HIDDEN + cc);
    tile[r][cc + 0] = f2bf(v.x);
    tile[r][cc + 1] = f2bf(v.y);
    tile[r][cc + 2] = f2bf(v.z);
    tile[r][cc + 3] = f2bf(v.w);
  }
  __syncthreads();
  const int nl = t >> 2;        // output row (n), 0..63
  const int kk = (t & 3) * 16;  // k chunk
  unsigned short tmp[16] __attribute__((aligned(16)));
#pragma unroll
  for (int j = 0; j < 16; ++j) tmp[j] = tile[kk + j][nl];
  unsigned short* dst = bt + ((size_t)l * HIDDEN + n0 + nl) * HIDDEN + k0 + kk;
  *(uint4*)(dst) = *(const uint4*)(tmp);
  *(uint4*)(dst + 8) = *(const uint4*)(tmp + 8);
}

// ---- per-layer GEMM: part[kz] = A[512][2048](bf16) @ Bt^T, partials in bf16 ----
// grid (32, 8, SPLITK) = 1024 blocks, 256 threads = 4 waves (2x2), wave tile 32x32.
// 3-buffer LDS, depth-2 prefetch, counted vmcnt (loads stay in flight across
// barriers -- the round-4 __syncthreads drained vmcnt(0) every tile, exposing
// the full global->LDS latency per K-tile).
__global__ __launch_bounds__(256, 3) void k_gemm(const unsigned short* __restrict__ A,
                                                 const unsigned short* __restrict__ Bt,
                                                 unsigned short* __restrict__ part) {
  __shared__ __attribute__((aligned(16))) unsigned short As[3][BM][BK];  // 24 KB
  __shared__ __attribute__((aligned(16))) unsigned short Bs[3][BN][BK];  // 24 KB

  const int n0 = blockIdx.x * BN;
  const int m0 = blockIdx.y * BM;
  const int kz = blockIdx.z;
  const int kbase = kz * KC;
  const int t = threadIdx.x;
  const int lane = t & 63;
  const int wid = t >> 6;
  const int wm = (wid >> 1) * 32;
  const int wn = (wid & 1) * 32;

  f32x4 zero = {0.f, 0.f, 0.f, 0.f};
  f32x4 acc[2][2];
  acc[0][0] = zero; acc[0][1] = zero; acc[1][0] = zero; acc[1][1] = zero;

  // T2 both-sides swizzle: pre-swizzled global source + linear LDS dest +
  // swizzled ds_read. Thread t stages chunk t (row t>>3) and t+256 (row +32);
  // (r+32)&7 == r&7 keeps the swizzled column valid for both.
  const int r0 = t >> 3;
  const int sc = ((t & 7) ^ (r0 & 7)) * 8;  // swizzled k-chunk (elements)
  const unsigned short* gA = A + (size_t)(m0 + r0) * HIDDEN + kbase + sc;
  const unsigned short* gB = Bt + (size_t)(n0 + r0) * HIDDEN + kbase + sc;
  char* lA = (char*)&As[0][0][0] + wid * 1024;  // + lane*16 implicit
  char* lB = (char*)&Bs[0][0][0] + wid * 1024;

#define STAGE(buf, kt)                                                     \
  do {                                                                     \
    const int ko = (kt)*BK;                                                \
    gload_lds16(gA + ko, lA + (buf)*8192);                                 \
    gload_lds16(gA + 32 * HIDDEN + ko, lA + (buf)*8192 + 4096);            \
    gload_lds16(gB + ko, lB + (buf)*8192);                                 \
    gload_lds16(gB + 32 * HIDDEN + ko, lB + (buf)*8192 + 4096);            \
  } while (0)

  const int row_a0 = wm + (lane & 15);
  const int row_a1 = row_a0 + 16;
  const int row_b0 = wn + (lane & 15);
  const int row_b1 = row_b0 + 16;
  const int q = lane >> 4;  // 0..3

#define COMPUTE(buf)                                                                    \
  do {                                                                                  \
    _Pragma("unroll") for (int ks = 0; ks < 2; ++ks) {                                  \
      const int cnk = ks * 4 + q;                                                       \
      bf16x8 a0 = *(const bf16x8*)&As[buf][row_a0][(cnk ^ (row_a0 & 7)) * 8];           \
      bf16x8 a1 = *(const bf16x8*)&As[buf][row_a1][(cnk ^ (row_a1 & 7)) * 8];           \
      bf16x8 b0 = *(const bf16x8*)&Bs[buf][row_b0][(cnk ^ (row_b0 & 7)) * 8];           \
      bf16x8 b1 = *(const bf16x8*)&Bs[buf][row_b1][(cnk ^ (row_b1 & 7)) * 8];           \
      acc[0][0] = __builtin_amdgcn_mfma_f32_16x16x32_bf16(a0, b0, acc[0][0], 0, 0, 0);  \
      acc[0][1] = __builtin_amdgcn_mfma_f32_16x16x32_bf16(a0, b1, acc[0][1], 0, 0, 0);  \
      acc[1][0] = __builtin_amdgcn_mfma_f32_16x16x32_bf16(a1, b0, acc[1][0], 0, 0, 0);  \
      acc[1][1] = __builtin_amdgcn_mfma_f32_16x16x32_bf16(a1, b1, acc[1][1], 0, 0, 0);  \
    }                                                                                   \
  } while (0)

  STAGE(0, 0);
  STAGE(1, 1);
#pragma unroll
  for (int kt = 0; kt < NT; ++kt) {
    const int s = kt % 3;
    // Barrier A: all waves done ds_reading the buffer we are about to re-stage
    // (lgkmcnt(0) first so no wave has an outstanding ds_read when the buffer
    // is overwritten -- MFMAs may sink past the barrier, ds_reads must not).
    asm volatile("s_waitcnt lgkmcnt(0)" ::: "memory");
    __builtin_amdgcn_s_barrier();
    if (kt + 2 < NT) STAGE((kt + 2) % 3, kt + 2);
    // Counted wait: stages kt..kt+2 in flight (4 loads each); retire oldest 4.
    if (kt < NT - 2)       asm volatile("s_waitcnt vmcnt(8)" ::: "memory");
    else if (kt == NT - 2) asm volatile("s_waitcnt vmcnt(4)" ::: "memory");
    else                   asm volatile("s_waitcnt vmcnt(0)" ::: "memory");
    __builtin_amdgcn_s_barrier();  // barrier B: stage kt visible to all waves
    COMPUTE(s);
  }

  unsigned short* p = part + (size_t)kz * ((size_t)BATCH * HIDDEN);
  const int rb = m0 + wm + (q << 2);
  const int cb = n0 + wn + (lane & 15);
#pragma unroll
  for (int fm = 0; fm < 2; ++fm)
#pragma unroll
    for (int fn = 0; fn < 2; ++fn)
#pragma unroll
      for (int j = 0; j < 4; ++j)
        p[(size_t)(rb + fm * 16 + j) * HIDDEN + cb + fn * 16] = f2bf(acc[fm][fn][j]);
}

// ---- per-layer epilogue: sum bf16 split-K partials, gate, tanh ----
__global__ __launch_bounds__(256) void k_reduce(const unsigned short* __restrict__ part,
                                                const float* __restrict__ prev,
                                                const float* __restrict__ ihl,
                                                const int* __restrict__ token,
                                                float* __restrict__ outf,
                                                unsigned short* __restrict__ outb) {
  const int idx = (blockIdx.x * 256 + threadIdx.x) * 4;
  const int m = idx >> 11;
  const int n = idx & 2047;
  const size_t MN = (size_t)BATCH * HIDDEN;
  float s[4] = {0.f, 0.f, 0.f, 0.f};
#pragma unroll
  for (int kz = 0; kz < SPLITK; ++kz) {
    union { uint2 u; unsigned short h[4]; } v;
    v.u = *(const uint2*)(part + kz * MN + idx);
#pragma unroll
    for (int j = 0; j < 4; ++j) s[j] += bf2f(v.h[j]);
  }
  float4 pv = *(const float4*)(prev + idx);
  const int tok = token[m];
  float4 g = *(const float4*)(ihl + (size_t)tok * HIDDEN + n);
  float4 r;
  r.x = tanh_fast(pv.x + s[0] * g.x);
  r.y = tanh_fast(pv.y + s[1] * g.y);
  r.z = tanh_fast(pv.z + s[2] * g.z);
  r.w = tanh_fast(pv.w + s[3] * g.w);
  *(float4*)(outf + idx) = r;
  if (outb) {
    union { unsigned short h[4]; uint2 u; } o;
    o.h[0] = f2bf(r.x); o.h[1] = f2bf(r.y); o.h[2] = f2bf(r.z); o.h[3] = f2bf(r.w);
    *(uint2*)(outb + idx) = o.u;
  }
}

extern "C" void kernel_launch(void* const* d_in, const int* in_sizes, int n_in,
                              void* d_out, int out_size, void* d_ws, size_t ws_size,
                              hipStream_t stream) {
  const float* state = (const float*)d_in[0];
  const int* token = (const int*)d_in[1];
  const float* ih = (const float*)d_in[2];
  const float* hh = (const float*)d_in[3];
  float* out = (float*)d_out;

  // ws layout (16B-aligned):
  //   Bt   : 6*2048*2048 bf16 = 50331648 B
  //   stb  : 512*2048 bf16    =  2097152 B
  //   sf   : 512*2048 f32     =  4194304 B
  //   part : 4*512*2048 bf16  =  8388608 B
  char* ws = (char*)d_ws;
  unsigned short* bt = (unsigned short*)ws;
  size_t off = (size_t)NLAYERS * HIDDEN * HIDDEN * 2;
  unsigned short* stb = (unsigned short*)(ws + off);
  off += (size_t)BATCH * HIDDEN * 2;
  float* sf = (float*)(ws + off);
  off += (size_t)BATCH * HIDDEN * 4;
  unsigned short* part = (unsigned short*)(ws + off);

  k_prep<<<dim3(HIDDEN / 64, HIDDEN / 64, NLAYERS + 1), 256, 0, stream>>>(hh, bt, state, stb);

  for (int l = 0; l < NLAYERS; ++l) {
    const bool last = (l == NLAYERS - 1);
    k_gemm<<<dim3(HIDDEN / BN, BATCH / BM, SPLITK), 256, 0, stream>>>(
        stb, bt + (size_t)l * HIDDEN * HIDDEN, part);
    k_reduce<<<dim3((BATCH * HIDDEN) / 1024), 256, 0, stream>>>(
        part, l == 0 ? state : sf, ih + (size_t)l * VOCAB * HIDDEN, token,
        last ? out : sf, last ? nullptr : stb);
  }
}

// Round 8
// 126.820 us; speedup vs baseline: 1.6697x; 1.0502x over previous
//
#include <hip/hip_runtime.h>
#include <hip/hip_bf16.h>
#include <cstdint>
#include <cstddef>

#define VOCAB 32000
#define HIDDEN 2048
#define NLAYERS 6
#define BATCH 512

// GEMM tiling (round-4 proven structure): M=512, N=2048, K=2048 per layer
#define BM 64
#define BN 64
#define BK 64
#define SPLITK 4
#define KC (HIDDEN / SPLITK)  // 512 K per block
#define NT (KC / BK)          // 8 K-tiles

typedef __attribute__((ext_vector_type(8))) short bf16x8;
typedef __attribute__((ext_vector_type(4))) float f32x4;

__device__ __forceinline__ unsigned short f2bf(float f) {
  unsigned u = __builtin_bit_cast(unsigned, f);
  u += 0x7fffu + ((u >> 16) & 1u);  // RNE
  return (unsigned short)(u >> 16);
}

__device__ __forceinline__ float bf2f(unsigned short h) {
  return __builtin_bit_cast(float, (unsigned)h << 16);
}

__device__ __forceinline__ float tanh_fast(float x) {
  x = fminf(15.f, fmaxf(-15.f, x));
  float e = __expf(2.f * x);
  return (e - 1.f) / (e + 1.f);
}

__device__ __forceinline__ void gload_lds16(const void* g, void* l) {
  __builtin_amdgcn_global_load_lds(
      (const __attribute__((address_space(1))) void*)g,
      (__attribute__((address_space(3))) void*)l, 16, 0, 0);
}

// ---- prep: z<NLAYERS: hh[l] fp32 [K][N] -> Bt bf16 [N][K]; z==NLAYERS: cvt state ----
__global__ __launch_bounds__(256) void k_prep(const float* __restrict__ hh,
                                              unsigned short* __restrict__ bt,
                                              const float* __restrict__ state,
                                              unsigned short* __restrict__ stb) {
  const int l = blockIdx.z;
  const int t = threadIdx.x;
  if (l == NLAYERS) {
    const int bid = blockIdx.y * 32 + blockIdx.x;
    const int i = (bid * 256 + t) * 4;
    float4 v = *(const float4*)(state + i);
    union { unsigned short h[4]; uint2 u; } o;
    o.h[0] = f2bf(v.x); o.h[1] = f2bf(v.y); o.h[2] = f2bf(v.z); o.h[3] = f2bf(v.w);
    *(uint2*)(stb + i) = o.u;
    return;
  }
  __shared__ unsigned short tile[64][72];  // padded to dodge bank conflicts
  const int n0 = blockIdx.x * 64;
  const int k0 = blockIdx.y * 64;
  const float* src = hh + ((size_t)l * HIDDEN + k0) * HIDDEN + n0;
  const int cr = t >> 4;        // 0..15
  const int cc = (t & 15) * 4;  // 0..60
#pragma unroll
  for (int p = 0; p < 4; ++p) {
    const int r = p * 16 + cr;
    float4 v = *(const float4*)(src + (size_t)r * HIDDEN + cc);
    tile[r][cc + 0] = f2bf(v.x);
    tile[r][cc + 1] = f2bf(v.y);
    tile[r][cc + 2] = f2bf(v.z);
    tile[r][cc + 3] = f2bf(v.w);
  }
  __syncthreads();
  const int nl = t >> 2;        // output row (n), 0..63
  const int kk = (t & 3) * 16;  // k chunk
  unsigned short tmp[16] __attribute__((aligned(16)));
#pragma unroll
  for (int j = 0; j < 16; ++j) tmp[j] = tile[kk + j][nl];
  unsigned short* dst = bt + ((size_t)l * HIDDEN + n0 + nl) * HIDDEN + k0 + kk;
  *(uint4*)(dst) = *(const uint4*)(tmp);
  *(uint4*)(dst + 8) = *(const uint4*)(tmp + 8);
}

// ---- per-layer GEMM: part[kz] = A[512][2048](bf16) @ Bt^T, partials in bf16 ----
// grid flat 1024 blocks = 4/CU, 256 threads = 4 waves (2x2), wave tile 32x32.
// XCD-local remap (T1): xcd = wgid%8 owns 4 fixed n-panels, so all B re-reads
// hit that XCD's L2 (4 panels x 256 KB + A 2 MB = 3 MB < 4 MB L2).
__global__ __launch_bounds__(256, 4) void k_gemm(const unsigned short* __restrict__ A,
                                                 const unsigned short* __restrict__ Bt,
                                                 unsigned short* __restrict__ part) {
  __shared__ __attribute__((aligned(16))) unsigned short As[2][BM][BK];
  __shared__ __attribute__((aligned(16))) unsigned short Bs[2][BN][BK];

  const int wgid = blockIdx.x;     // 0..1023, flat
  const int xcd = wgid & 7;        // dispatch round-robin heuristic (HK)
  const int idx = wgid >> 3;       // 0..127
  const int n0 = (xcd * 4 + (idx & 3)) * BN;  // n-panel, 4 per XCD
  const int m0 = ((idx >> 2) & 7) * BM;       // m-panel 0..7
  const int kz = idx >> 5;                    // 0..3
  const int kbase = kz * KC;
  const int t = threadIdx.x;
  const int lane = t & 63;
  const int wid = t >> 6;
  const int wm = (wid >> 1) * 32;
  const int wn = (wid & 1) * 32;

  f32x4 zero = {0.f, 0.f, 0.f, 0.f};
  f32x4 acc[2][2];
  acc[0][0] = zero; acc[0][1] = zero; acc[1][0] = zero; acc[1][1] = zero;

  // T2 both-sides swizzle: pre-swizzled global source + linear LDS dest +
  // swizzled ds_read. Thread t stages chunk t (row t>>3) and t+256 (row +32);
  // (r+32)&7 == r&7 keeps the swizzled column valid for both.
  const int r0 = t >> 3;
  const int sc = ((t & 7) ^ (r0 & 7)) * 8;  // swizzled k-chunk (elements)
  const unsigned short* gA = A + (size_t)(m0 + r0) * HIDDEN + kbase + sc;
  const unsigned short* gB = Bt + (size_t)(n0 + r0) * HIDDEN + kbase + sc;
  char* lA = (char*)&As[0][0][0] + wid * 1024;  // + lane*16 implicit
  char* lB = (char*)&Bs[0][0][0] + wid * 1024;

#define STAGE(buf, kt)                                                     \
  do {                                                                     \
    const int ko = (kt)*BK;                                                \
    gload_lds16(gA + ko, lA + (buf)*8192);                                 \
    gload_lds16(gA + 32 * HIDDEN + ko, lA + (buf)*8192 + 4096);            \
    gload_lds16(gB + ko, lB + (buf)*8192);                                 \
    gload_lds16(gB + 32 * HIDDEN + ko, lB + (buf)*8192 + 4096);            \
  } while (0)

  const int row_a0 = wm + (lane & 15);
  const int row_a1 = row_a0 + 16;
  const int row_b0 = wn + (lane & 15);
  const int row_b1 = row_b0 + 16;
  const int q = lane >> 4;  // 0..3

#define COMPUTE(buf)                                                                    \
  do {                                                                                  \
    _Pragma("unroll") for (int ks = 0; ks < 2; ++ks) {                                  \
      const int cnk = ks * 4 + q;                                                       \
      bf16x8 a0 = *(const bf16x8*)&As[buf][row_a0][(cnk ^ (row_a0 & 7)) * 8];           \
      bf16x8 a1 = *(const bf16x8*)&As[buf][row_a1][(cnk ^ (row_a1 & 7)) * 8];           \
      bf16x8 b0 = *(const bf16x8*)&Bs[buf][row_b0][(cnk ^ (row_b0 & 7)) * 8];           \
      bf16x8 b1 = *(const bf16x8*)&Bs[buf][row_b1][(cnk ^ (row_b1 & 7)) * 8];           \
      acc[0][0] = __builtin_amdgcn_mfma_f32_16x16x32_bf16(a0, b0, acc[0][0], 0, 0, 0);  \
      acc[0][1] = __builtin_amdgcn_mfma_f32_16x16x32_bf16(a0, b1, acc[0][1], 0, 0, 0);  \
      acc[1][0] = __builtin_amdgcn_mfma_f32_16x16x32_bf16(a1, b0, acc[1][0], 0, 0, 0);  \
      acc[1][1] = __builtin_amdgcn_mfma_f32_16x16x32_bf16(a1, b1, acc[1][1], 0, 0, 0);  \
    }                                                                                   \
  } while (0)

  STAGE(0, 0);
  __syncthreads();
  for (int kt = 0; kt < NT; ++kt) {
    const int buf = kt & 1;
    if (kt + 1 < NT) STAGE(buf ^ 1, kt + 1);
    COMPUTE(buf);
    __syncthreads();
  }

  unsigned short* p = part + (size_t)kz * ((size_t)BATCH * HIDDEN);
  const int rb = m0 + wm + (q << 2);
  const int cb = n0 + wn + (lane & 15);
#pragma unroll
  for (int fm = 0; fm < 2; ++fm)
#pragma unroll
    for (int fn = 0; fn < 2; ++fn)
#pragma unroll
      for (int j = 0; j < 4; ++j)
        p[(size_t)(rb + fm * 16 + j) * HIDDEN + cb + fn * 16] = f2bf(acc[fm][fn][j]);
}

// ---- per-layer epilogue: sum bf16 split-K partials, gate, tanh ----
__global__ __launch_bounds__(256) void k_reduce(const unsigned short* __restrict__ part,
                                                const float* __restrict__ prev,
                                                const float* __restrict__ ihl,
                                                const int* __restrict__ token,
                                                float* __restrict__ outf,
                                                unsigned short* __restrict__ outb) {
  const int idx = (blockIdx.x * 256 + threadIdx.x) * 4;
  const int m = idx >> 11;
  const int n = idx & 2047;
  const size_t MN = (size_t)BATCH * HIDDEN;
  float s[4] = {0.f, 0.f, 0.f, 0.f};
#pragma unroll
  for (int kz = 0; kz < SPLITK; ++kz) {
    union { uint2 u; unsigned short h[4]; } v;
    v.u = *(const uint2*)(part + kz * MN + idx);
#pragma unroll
    for (int j = 0; j < 4; ++j) s[j] += bf2f(v.h[j]);
  }
  float4 pv = *(const float4*)(prev + idx);
  const int tok = token[m];
  float4 g = *(const float4*)(ihl + (size_t)tok * HIDDEN + n);
  float4 r;
  r.x = tanh_fast(pv.x + s[0] * g.x);
  r.y = tanh_fast(pv.y + s[1] * g.y);
  r.z = tanh_fast(pv.z + s[2] * g.z);
  r.w = tanh_fast(pv.w + s[3] * g.w);
  *(float4*)(outf + idx) = r;
  if (outb) {
    union { unsigned short h[4]; uint2 u; } o;
    o.h[0] = f2bf(r.x); o.h[1] = f2bf(r.y); o.h[2] = f2bf(r.z); o.h[3] = f2bf(r.w);
    *(uint2*)(outb + idx) = o.u;
  }
}

extern "C" void kernel_launch(void* const* d_in, const int* in_sizes, int n_in,
                              void* d_out, int out_size, void* d_ws, size_t ws_size,
                              hipStream_t stream) {
  const float* state = (const float*)d_in[0];
  const int* token = (const int*)d_in[1];
  const float* ih = (const float*)d_in[2];
  const float* hh = (const float*)d_in[3];
  float* out = (float*)d_out;

  // ws layout (16B-aligned):
  //   Bt   : 6*2048*2048 bf16 = 50331648 B
  //   stb  : 512*2048 bf16    =  2097152 B
  //   sf   : 512*2048 f32     =  4194304 B
  //   part : 4*512*2048 bf16  =  8388608 B
  char* ws = (char*)d_ws;
  unsigned short* bt = (unsigned short*)ws;
  size_t off = (size_t)NLAYERS * HIDDEN * HIDDEN * 2;
  unsigned short* stb = (unsigned short*)(ws + off);
  off += (size_t)BATCH * HIDDEN * 2;
  float* sf = (float*)(ws + off);
  off += (size_t)BATCH * HIDDEN * 4;
  unsigned short* part = (unsigned short*)(ws + off);

  k_prep<<<dim3(HIDDEN / 64, HIDDEN / 64, NLAYERS + 1), 256, 0, stream>>>(hh, bt, state, stb);

  for (int l = 0; l < NLAYERS; ++l) {
    const bool last = (l == NLAYERS - 1);
    k_gemm<<<dim3(SPLITK * (HIDDEN / BN) * (BATCH / BM)), 256, 0, stream>>>(
        stb, bt + (size_t)l * HIDDEN * HIDDEN, part);
    k_reduce<<<dim3((BATCH * HIDDEN) / 1024), 256, 0, stream>>>(
        part, l == 0 ? state : sf, ih + (size_t)l * VOCAB * HIDDEN, token,
        last ? out : sf, last ? nullptr : stb);
  }
}